// Round 1
// baseline (544.735 us; speedup 1.0000x reference)
//
#include <hip/hip_runtime.h>

typedef unsigned short u16;
typedef __bf16 bf16x8 __attribute__((ext_vector_type(8)));
typedef float f32x4 __attribute__((ext_vector_type(4)));

#define SEQ_LEN 4096
#define HID 1024
#define NHEAD 16
#define HDIM 64
#define MROWS 8192   // B*S

__device__ __forceinline__ u16 f2bf(float f) {
  union { float f; unsigned u; } v; v.f = f;
  unsigned r = v.u + 0x7fffu + ((v.u >> 16) & 1u);
  return (u16)(r >> 16);
}

__device__ __forceinline__ void gload16(const void* g, void* lds) {
  __builtin_amdgcn_global_load_lds((const __attribute__((address_space(1))) void*)g,
                                   (__attribute__((address_space(3))) void*)lds, 16, 0, 0);
}

// ---------------- conversion kernels ----------------

__global__ void cvt_x_kernel(const float* __restrict__ src, u16* __restrict__ dst, int n4) {
  int stride = gridDim.x * blockDim.x;
  for (int i = blockIdx.x * blockDim.x + threadIdx.x; i < n4; i += stride) {
    float4 v = ((const float4*)src)[i];
    ((ushort4*)dst)[i] = make_ushort4(f2bf(v.x), f2bf(v.y), f2bf(v.z), f2bf(v.w));
  }
}

__global__ void cvt_w_kernel(const float* __restrict__ w0, const float* __restrict__ w1,
                             const float* __restrict__ w2, const float* __restrict__ w3,
                             u16* __restrict__ dst) {
  const float* src = (blockIdx.y == 0) ? w0 : (blockIdx.y == 1) ? w1 : (blockIdx.y == 2) ? w2 : w3;
  u16* d = dst + (size_t)blockIdx.y * (HID * HID);
  int i = blockIdx.x * blockDim.x + threadIdx.x;   // 1024 blocks * 256 = exactly HID*HID/4
  float4 v = ((const float4*)src)[i];
  ((ushort4*)d)[i] = make_ushort4(f2bf(v.x), f2bf(v.y), f2bf(v.z), f2bf(v.w));
}

__global__ void maskchk_kernel(const float* __restrict__ mask, int n4, int* flag) {
  int stride = gridDim.x * blockDim.x;
  bool nz = false;
  for (int i = blockIdx.x * blockDim.x + threadIdx.x; i < n4; i += stride) {
    float4 v = ((const float4*)mask)[i];
    nz |= (v.x != 0.f) | (v.y != 0.f) | (v.z != 0.f) | (v.w != 0.f);
  }
  if (__any(nz) && (threadIdx.x & 63) == 0) atomicOr(flag, 1);
}

// ---------------- GEMM core (y = A @ W^T), 128x128 tile, BK=64 ----------------
// A: MROWS x 1024 bf16, W: 1024 x 1024 bf16 (rows=n, cols=k). LDS XOR-swizzled.

__device__ __forceinline__ void gemm_core(const u16* __restrict__ A, const u16* __restrict__ W,
                                          int m0, int n0, char* As, char* Bs, f32x4 acc[4][4]) {
  const int t = threadIdx.x, w = t >> 6, l = t & 63;
  const int lr = l & 15, lg = l >> 4;
  const int wr = (w >> 1) * 64, wc = (w & 1) * 64;
#pragma unroll
  for (int i = 0; i < 4; i++)
#pragma unroll
    for (int j = 0; j < 4; j++) acc[i][j] = (f32x4){0.f, 0.f, 0.f, 0.f};

  for (int k0 = 0; k0 < HID; k0 += 64) {
    __syncthreads();
#pragma unroll
    for (int j = 0; j < 4; j++) {
      int o = w * 4096 + j * 1024 + l * 16;
      int row = o >> 7, kb = (o >> 4) & 7, skb = kb ^ (row & 7);
      gload16(A + (size_t)(m0 + row) * HID + k0 + skb * 8, As + (w * 4096 + j * 1024));
      gload16(W + (size_t)(n0 + row) * HID + k0 + skb * 8, Bs + (w * 4096 + j * 1024));
    }
    __syncthreads();
#pragma unroll
    for (int ks = 0; ks < 2; ks++) {
      bf16x8 af[4], bf[4];
      int kb = ks * 4 + lg;
#pragma unroll
      for (int mt = 0; mt < 4; mt++) {
        int row = wr + mt * 16 + lr;
        af[mt] = *(const bf16x8*)(As + row * 128 + ((kb ^ (row & 7)) << 4));
      }
#pragma unroll
      for (int nt = 0; nt < 4; nt++) {
        int row = wc + nt * 16 + lr;
        bf[nt] = *(const bf16x8*)(Bs + row * 128 + ((kb ^ (row & 7)) << 4));
      }
#pragma unroll
      for (int mt = 0; mt < 4; mt++)
#pragma unroll
        for (int nt = 0; nt < 4; nt++)
          acc[mt][nt] = __builtin_amdgcn_mfma_f32_16x16x32_bf16(af[mt], bf[nt], acc[mt][nt], 0, 0, 0);
    }
  }
}

// QKV GEMM: gridDim = (64, 24). n-global in [0,3072): mat 0=Q (prescale 1/8), 1=K, 2=V (transposed store)
__global__ __launch_bounds__(256) void gemm_qkv_kernel(
    const u16* __restrict__ xb, const u16* __restrict__ wqb, const u16* __restrict__ wkb,
    const u16* __restrict__ wvb, const float* __restrict__ bq, const float* __restrict__ bk,
    const float* __restrict__ bv, u16* __restrict__ Qb, u16* __restrict__ Kb, u16* __restrict__ VT) {
  __shared__ __align__(128) char lds[32768];
  int m0 = blockIdx.x * 128;
  int ng = blockIdx.y * 128;
  int mat = ng >> 10, n0 = ng & 1023;
  const u16* W = (mat == 0) ? wqb : (mat == 1) ? wkb : wvb;
  const float* bias = (mat == 0) ? bq : (mat == 1) ? bk : bv;
  f32x4 acc[4][4];
  gemm_core(xb, W, m0, n0, lds, lds + 16384, acc);

  const int t = threadIdx.x, w = t >> 6, l = t & 63;
  const int lr = l & 15, lg = l >> 4;
  if (mat < 2) {
    u16* dst = (mat == 0) ? Qb : Kb;
    float scale = (mat == 0) ? 0.125f : 1.0f;
#pragma unroll
    for (int mt = 0; mt < 4; mt++)
#pragma unroll
      for (int nt = 0; nt < 4; nt++) {
        int n = n0 + (w & 1) * 64 + nt * 16 + lr;
        float bn = bias[n];
#pragma unroll
        for (int i = 0; i < 4; i++) {
          int m = m0 + (w >> 1) * 64 + mt * 16 + lg * 4 + i;
          dst[(size_t)m * HID + n] = f2bf((acc[mt][nt][i] + bn) * scale);
        }
      }
  } else {
    // V^T store: VT[b][h][d][s], 4 consecutive s per lane -> packed 8B store
#pragma unroll
    for (int mt = 0; mt < 4; mt++)
#pragma unroll
      for (int nt = 0; nt < 4; nt++) {
        int m = m0 + (w >> 1) * 64 + mt * 16 + lg * 4;  // s base (4 consecutive)
        int n = n0 + (w & 1) * 64 + nt * 16 + lr;       // d-global in [0,1024)
        int b = m >> 12, s = m & 4095;
        int h = n >> 6, d = n & 63;
        float bn = bias[n];
        ushort4 pk = make_ushort4(f2bf(acc[mt][nt][0] + bn), f2bf(acc[mt][nt][1] + bn),
                                  f2bf(acc[mt][nt][2] + bn), f2bf(acc[mt][nt][3] + bn));
        *(ushort4*)(VT + (((size_t)(b * NHEAD + h) * HDIM + d) * SEQ_LEN + s)) = pk;
      }
  }
}

// out-proj GEMM: gridDim = (64, 8), fp32 output + bias
__global__ __launch_bounds__(256) void gemm_out_kernel(
    const u16* __restrict__ Ob, const u16* __restrict__ wob, const float* __restrict__ bo,
    float* __restrict__ out) {
  __shared__ __align__(128) char lds[32768];
  int m0 = blockIdx.x * 128, n0 = blockIdx.y * 128;
  f32x4 acc[4][4];
  gemm_core(Ob, wob, m0, n0, lds, lds + 16384, acc);
  const int t = threadIdx.x, w = t >> 6, l = t & 63;
  const int lr = l & 15, lg = l >> 4;
#pragma unroll
  for (int mt = 0; mt < 4; mt++)
#pragma unroll
    for (int nt = 0; nt < 4; nt++) {
      int n = n0 + (w & 1) * 64 + nt * 16 + lr;
      float bn = bo[n];
#pragma unroll
      for (int i = 0; i < 4; i++) {
        int m = m0 + (w >> 1) * 64 + mt * 16 + lg * 4 + i;
        out[(size_t)m * HID + n] = acc[mt][nt][i] + bn;
      }
    }
}

// ---------------- flash attention ----------------
// grid = (64, 32): q0 = bx*64; by = b*16+h. 256 threads, wave w owns q-strip rows [w*16, w*16+16).
__global__ __launch_bounds__(256) void attn_kernel(
    const u16* __restrict__ Qb, const u16* __restrict__ Kb, const u16* __restrict__ VT,
    const float* __restrict__ mask, const int* __restrict__ flag, u16* __restrict__ Ob) {
  __shared__ __align__(128) char lds[32768];
  char* Qs = lds;            // 64 x 128B (64 bf16 per row), swizzled
  char* Ks = lds + 8192;
  char* Vs = lds + 16384;    // VT tile: 64 d-rows x 64 kv
  char* Ps = lds + 24576;    // per-wave 16 x 128B regions
  const int q0 = blockIdx.x * 64;
  const int bh = blockIdx.y, b = bh >> 4, h = bh & 15;
  const int t = threadIdx.x, w = t >> 6, l = t & 63;
  const int lr = l & 15, lg = l >> 4;
  const bool useMask = (flag[0] != 0);

  // stage Q tile (rows b*4096+q0 .. +63, cols h*64..h*64+63)
#pragma unroll
  for (int j = 0; j < 2; j++) {
    int o = w * 2048 + j * 1024 + l * 16;
    int row = o >> 7, kb = (o >> 4) & 7, skb = kb ^ (row & 7);
    gload16(Qb + ((size_t)(b * SEQ_LEN + q0 + row) * HID + h * HDIM + skb * 8),
            Qs + (w * 2048 + j * 1024));
  }

  f32x4 oacc[4];
#pragma unroll
  for (int dt = 0; dt < 4; dt++) oacc[dt] = (f32x4){0.f, 0.f, 0.f, 0.f};
  float m_r[4] = {-1e30f, -1e30f, -1e30f, -1e30f};
  float l_r[4] = {0.f, 0.f, 0.f, 0.f};

  for (int kv0 = 0; kv0 < SEQ_LEN; kv0 += 64) {
    __syncthreads();   // previous iter's PV done (and Q drained on first iter)
#pragma unroll
    for (int j = 0; j < 2; j++) {
      int o = w * 2048 + j * 1024 + l * 16;
      int row = o >> 7, kb = (o >> 4) & 7, skb = kb ^ (row & 7);
      gload16(Kb + ((size_t)(b * SEQ_LEN + kv0 + row) * HID + h * HDIM + skb * 8),
              Ks + (w * 2048 + j * 1024));
      gload16(VT + (((size_t)(b * NHEAD + h) * HDIM + row) * SEQ_LEN + kv0 + skb * 8),
              Vs + (w * 2048 + j * 1024));
    }
    __syncthreads();   // staging complete

    // S = Q K^T (Q pre-scaled by 1/8): per-wave 16x64 strip
    f32x4 sf[4];
#pragma unroll
    for (int kt = 0; kt < 4; kt++) sf[kt] = (f32x4){0.f, 0.f, 0.f, 0.f};
#pragma unroll
    for (int ks = 0; ks < 2; ks++) {
      int kb = ks * 4 + lg;
      int arow = w * 16 + lr;
      bf16x8 aq = *(const bf16x8*)(Qs + arow * 128 + ((kb ^ (arow & 7)) << 4));
#pragma unroll
      for (int kt = 0; kt < 4; kt++) {
        int krow = kt * 16 + lr;
        bf16x8 bk8 = *(const bf16x8*)(Ks + krow * 128 + ((kb ^ (krow & 7)) << 4));
        sf[kt] = __builtin_amdgcn_mfma_f32_16x16x32_bf16(aq, bk8, sf[kt], 0, 0, 0);
      }
    }

    if (useMask) {   // slow path: per-element mask add (benchmark mask is all-zero -> skipped)
#pragma unroll
      for (int kt = 0; kt < 4; kt++)
#pragma unroll
        for (int i = 0; i < 4; i++) {
          int q = q0 + w * 16 + lg * 4 + i;
          int k = kv0 + kt * 16 + lr;
          sf[kt][i] += mask[(size_t)q * SEQ_LEN + k];
        }
    }

    // online softmax per row (rows lg*4+i owned by 16-lane group)
    float scf[4];
#pragma unroll
    for (int i = 0; i < 4; i++) {
      float mx = fmaxf(fmaxf(sf[0][i], sf[1][i]), fmaxf(sf[2][i], sf[3][i]));
      mx = fmaxf(mx, __shfl_xor(mx, 1));
      mx = fmaxf(mx, __shfl_xor(mx, 2));
      mx = fmaxf(mx, __shfl_xor(mx, 4));
      mx = fmaxf(mx, __shfl_xor(mx, 8));
      float nm = fmaxf(m_r[i], mx);
      scf[i] = __expf(m_r[i] - nm);
      m_r[i] = nm;
    }
#pragma unroll
    for (int i = 0; i < 4; i++) {
      float s = 0.f;
#pragma unroll
      for (int kt = 0; kt < 4; kt++) {
        float p = __expf(sf[kt][i] - m_r[i]);
        sf[kt][i] = p;
        s += p;
      }
      s += __shfl_xor(s, 1);
      s += __shfl_xor(s, 2);
      s += __shfl_xor(s, 4);
      s += __shfl_xor(s, 8);
      l_r[i] = l_r[i] * scf[i] + s;
#pragma unroll
      for (int dt = 0; dt < 4; dt++) oacc[dt][i] *= scf[i];
    }

    // write P (bf16) to per-wave LDS region, swizzled
#pragma unroll
    for (int kt = 0; kt < 4; kt++)
#pragma unroll
      for (int i = 0; i < 4; i++) {
        int row = lg * 4 + i;
        int col = kt * 16 + lr;
        int kb = col >> 3;
        *(u16*)(Ps + w * 2048 + row * 128 + ((kb ^ (row & 7)) << 4) + (col & 7) * 2) =
            f2bf(sf[kt][i]);
      }
    __syncthreads();   // P visible (and ordering guard)

    // O += P @ V  (Vt rows are d, contiguous in kv)
#pragma unroll
    for (int ks = 0; ks < 2; ks++) {
      int kb = ks * 4 + lg;
      int prow = lr;
      bf16x8 ap = *(const bf16x8*)(Ps + w * 2048 + prow * 128 + ((kb ^ (prow & 7)) << 4));
#pragma unroll
      for (int dt = 0; dt < 4; dt++) {
        int vrow = dt * 16 + lr;
        bf16x8 bv8 = *(const bf16x8*)(Vs + vrow * 128 + ((kb ^ (vrow & 7)) << 4));
        oacc[dt] = __builtin_amdgcn_mfma_f32_16x16x32_bf16(ap, bv8, oacc[dt], 0, 0, 0);
      }
    }
  }

  // epilogue: normalize and store O (bf16, row-major (b s, h*64+d))
#pragma unroll
  for (int dt = 0; dt < 4; dt++)
#pragma unroll
    for (int i = 0; i < 4; i++) {
      float v = oacc[dt][i] / l_r[i];
      int m = b * SEQ_LEN + q0 + w * 16 + lg * 4 + i;
      int n = h * HDIM + dt * 16 + lr;
      Ob[(size_t)m * HID + n] = f2bf(v);
    }
}

// ---------------- launch ----------------

extern "C" void kernel_launch(void* const* d_in, const int* in_sizes, int n_in,
                              void* d_out, int out_size, void* d_ws, size_t ws_size,
                              hipStream_t stream) {
  const float* x    = (const float*)d_in[0];
  const float* mask = (const float*)d_in[1];
  const float* wq   = (const float*)d_in[2];
  const float* bq   = (const float*)d_in[3];
  const float* wk   = (const float*)d_in[4];
  const float* bk   = (const float*)d_in[5];
  const float* wv   = (const float*)d_in[6];
  const float* bv   = (const float*)d_in[7];
  const float* wo   = (const float*)d_in[8];
  const float* bo   = (const float*)d_in[9];

  char* ws = (char*)d_ws;
  u16* xb  = (u16*)(ws + 0);          // 16 MB (reused as Ob after QKV GEMM)
  u16* wqb = (u16*)(ws + 16777216);   // 2 MB
  u16* wkb = (u16*)(ws + 18874368);
  u16* wvb = (u16*)(ws + 20971520);
  u16* wob = (u16*)(ws + 23068672);
  u16* Qb  = (u16*)(ws + 25165824);   // 16 MB
  u16* Kb  = (u16*)(ws + 41943040);   // 16 MB
  u16* VT  = (u16*)(ws + 58720256);   // 16 MB
  int* flag = (int*)(ws + 75497472);
  u16* Ob = xb;

  hipMemsetAsync(flag, 0, 4, stream);
  cvt_x_kernel<<<2048, 256, 0, stream>>>(x, xb, MROWS * HID / 4);
  cvt_w_kernel<<<dim3(1024, 4), 256, 0, stream>>>(wq, wk, wv, wo, wqb);
  maskchk_kernel<<<2048, 256, 0, stream>>>(mask, SEQ_LEN * SEQ_LEN / 4, flag);
  gemm_qkv_kernel<<<dim3(64, 24), 256, 0, stream>>>(xb, wqb, wkb, wvb, bq, bk, bv, Qb, Kb, VT);
  attn_kernel<<<dim3(64, 32), 256, 0, stream>>>(Qb, Kb, VT, mask, flag, Ob);
  gemm_out_kernel<<<dim3(64, 8), 256, 0, stream>>>(Ob, wob, bo, (float*)d_out);
}

// Round 3
// 424.774 us; speedup vs baseline: 1.2824x; 1.2824x over previous
//
#include <hip/hip_runtime.h>

typedef unsigned short u16;
typedef __bf16 bf16x4 __attribute__((ext_vector_type(4)));
typedef __bf16 bf16x8 __attribute__((ext_vector_type(8)));
typedef float f32x4 __attribute__((ext_vector_type(4)));

#define SEQ_LEN 4096
#define HID 1024
#define NHEAD 16
#define HDIM 64
#define MROWS 8192   // B*S
#define LOG2E 1.44269504088896f

__device__ __forceinline__ u16 f2bf(float f) {
  union { float f; unsigned u; } v; v.f = f;
  unsigned r = v.u + 0x7fffu + ((v.u >> 16) & 1u);
  return (u16)(r >> 16);
}

__device__ __forceinline__ void gload16(const void* g, void* lds) {
  __builtin_amdgcn_global_load_lds((const __attribute__((address_space(1))) void*)g,
                                   (__attribute__((address_space(3))) void*)lds, 16, 0, 0);
}

// ---------------- conversion kernels ----------------

__global__ void cvt_x_kernel(const float* __restrict__ src, u16* __restrict__ dst, int n4) {
  int stride = gridDim.x * blockDim.x;
  for (int i = blockIdx.x * blockDim.x + threadIdx.x; i < n4; i += stride) {
    float4 v = ((const float4*)src)[i];
    ((ushort4*)dst)[i] = make_ushort4(f2bf(v.x), f2bf(v.y), f2bf(v.z), f2bf(v.w));
  }
}

__global__ void cvt_w_kernel(const float* __restrict__ w0, const float* __restrict__ w1,
                             const float* __restrict__ w2, const float* __restrict__ w3,
                             u16* __restrict__ dst) {
  const float* src = (blockIdx.y == 0) ? w0 : (blockIdx.y == 1) ? w1 : (blockIdx.y == 2) ? w2 : w3;
  u16* d = dst + (size_t)blockIdx.y * (HID * HID);
  int i = blockIdx.x * blockDim.x + threadIdx.x;
  float4 v = ((const float4*)src)[i];
  ((ushort4*)d)[i] = make_ushort4(f2bf(v.x), f2bf(v.y), f2bf(v.z), f2bf(v.w));
}

__global__ void maskchk_kernel(const float* __restrict__ mask, int n4, int* flag) {
  int stride = gridDim.x * blockDim.x;
  bool nz = false;
  for (int i = blockIdx.x * blockDim.x + threadIdx.x; i < n4; i += stride) {
    float4 v = ((const float4*)mask)[i];
    nz |= (v.x != 0.f) | (v.y != 0.f) | (v.z != 0.f) | (v.w != 0.f);
  }
  if (__any(nz) && (threadIdx.x & 63) == 0) atomicOr(flag, 1);
}

// ---------------- GEMM core (y = A @ W^T), 128x128 tile, BK=64 ----------------

__device__ __forceinline__ void gemm_core(const u16* __restrict__ A, const u16* __restrict__ W,
                                          int m0, int n0, char* As, char* Bs, f32x4 acc[4][4]) {
  const int t = threadIdx.x, w = t >> 6, l = t & 63;
  const int lr = l & 15, lg = l >> 4;
  const int wr = (w >> 1) * 64, wc = (w & 1) * 64;
#pragma unroll
  for (int i = 0; i < 4; i++)
#pragma unroll
    for (int j = 0; j < 4; j++) acc[i][j] = (f32x4){0.f, 0.f, 0.f, 0.f};

  for (int k0 = 0; k0 < HID; k0 += 64) {
    __syncthreads();
#pragma unroll
    for (int j = 0; j < 4; j++) {
      int o = w * 4096 + j * 1024 + l * 16;
      int row = o >> 7, kb = (o >> 4) & 7, skb = kb ^ (row & 7);
      gload16(A + (size_t)(m0 + row) * HID + k0 + skb * 8, As + (w * 4096 + j * 1024));
      gload16(W + (size_t)(n0 + row) * HID + k0 + skb * 8, Bs + (w * 4096 + j * 1024));
    }
    __syncthreads();
#pragma unroll
    for (int ks = 0; ks < 2; ks++) {
      bf16x8 af[4], bf[4];
      int kb = ks * 4 + lg;
#pragma unroll
      for (int mt = 0; mt < 4; mt++) {
        int row = wr + mt * 16 + lr;
        af[mt] = *(const bf16x8*)(As + row * 128 + ((kb ^ (row & 7)) << 4));
      }
#pragma unroll
      for (int nt = 0; nt < 4; nt++) {
        int row = wc + nt * 16 + lr;
        bf[nt] = *(const bf16x8*)(Bs + row * 128 + ((kb ^ (row & 7)) << 4));
      }
#pragma unroll
      for (int mt = 0; mt < 4; mt++)
#pragma unroll
        for (int nt = 0; nt < 4; nt++)
          acc[mt][nt] = __builtin_amdgcn_mfma_f32_16x16x32_bf16(af[mt], bf[nt], acc[mt][nt], 0, 0, 0);
    }
  }
}

// QKV GEMM: gridDim = (64, 24). mat 0=Q (prescale log2e/8), 1=K, 2=V (transposed store)
__global__ __launch_bounds__(256) void gemm_qkv_kernel(
    const u16* __restrict__ xb, const u16* __restrict__ wqb, const u16* __restrict__ wkb,
    const u16* __restrict__ wvb, const float* __restrict__ bq, const float* __restrict__ bk,
    const float* __restrict__ bv, u16* __restrict__ Qb, u16* __restrict__ Kb, u16* __restrict__ VT) {
  __shared__ __align__(128) char lds[32768];
  int m0 = blockIdx.x * 128;
  int ng = blockIdx.y * 128;
  int mat = ng >> 10, n0 = ng & 1023;
  const u16* W = (mat == 0) ? wqb : (mat == 1) ? wkb : wvb;
  const float* bias = (mat == 0) ? bq : (mat == 1) ? bk : bv;
  f32x4 acc[4][4];
  gemm_core(xb, W, m0, n0, lds, lds + 16384, acc);

  const int t = threadIdx.x, w = t >> 6, l = t & 63;
  const int lr = l & 15, lg = l >> 4;
  if (mat < 2) {
    u16* dst = (mat == 0) ? Qb : Kb;
    float scale = (mat == 0) ? 0.125f * LOG2E : 1.0f;
#pragma unroll
    for (int mt = 0; mt < 4; mt++)
#pragma unroll
      for (int nt = 0; nt < 4; nt++) {
        int n = n0 + (w & 1) * 64 + nt * 16 + lr;
        float bn = bias[n];
#pragma unroll
        for (int i = 0; i < 4; i++) {
          int m = m0 + (w >> 1) * 64 + mt * 16 + lg * 4 + i;
          dst[(size_t)m * HID + n] = f2bf((acc[mt][nt][i] + bn) * scale);
        }
      }
  } else {
#pragma unroll
    for (int mt = 0; mt < 4; mt++)
#pragma unroll
      for (int nt = 0; nt < 4; nt++) {
        int m = m0 + (w >> 1) * 64 + mt * 16 + lg * 4;  // s base (4 consecutive)
        int n = n0 + (w & 1) * 64 + nt * 16 + lr;       // d-global
        int b = m >> 12, s = m & 4095;
        int h = n >> 6, d = n & 63;
        float bn = bias[n];
        ushort4 pk = make_ushort4(f2bf(acc[mt][nt][0] + bn), f2bf(acc[mt][nt][1] + bn),
                                  f2bf(acc[mt][nt][2] + bn), f2bf(acc[mt][nt][3] + bn));
        *(ushort4*)(VT + (((size_t)(b * NHEAD + h) * HDIM + d) * SEQ_LEN + s)) = pk;
      }
  }
}

// out-proj GEMM: gridDim = (64, 8), fp32 output + bias
__global__ __launch_bounds__(256) void gemm_out_kernel(
    const u16* __restrict__ Ob, const u16* __restrict__ wob, const float* __restrict__ bo,
    float* __restrict__ out) {
  __shared__ __align__(128) char lds[32768];
  int m0 = blockIdx.x * 128, n0 = blockIdx.y * 128;
  f32x4 acc[4][4];
  gemm_core(Ob, wob, m0, n0, lds, lds + 16384, acc);
  const int t = threadIdx.x, w = t >> 6, l = t & 63;
  const int lr = l & 15, lg = l >> 4;
#pragma unroll
  for (int mt = 0; mt < 4; mt++)
#pragma unroll
    for (int nt = 0; nt < 4; nt++) {
      int n = n0 + (w & 1) * 64 + nt * 16 + lr;
      float bn = bo[n];
#pragma unroll
      for (int i = 0; i < 4; i++) {
        int m = m0 + (w >> 1) * 64 + mt * 16 + lg * 4 + i;
        out[(size_t)m * HID + n] = acc[mt][nt][i] + bn;
      }
    }
}

// ---------------- flash attention (swapped QK^T, in-register softmax) ----------------
// grid = (64, 32): q0 = bx*64; by = b*16+h. 4 waves; wave w owns q rows [w*16, w*16+16).
// S^T = K . Q^T so each lane holds one q-row's scores; P stays in registers for PV.
__global__ __launch_bounds__(256) void attn_kernel(
    const u16* __restrict__ Qb, const u16* __restrict__ Kb, const u16* __restrict__ VT,
    const float* __restrict__ mask, const int* __restrict__ flag, u16* __restrict__ Ob) {
  __shared__ __align__(128) char lds[32768];
  // layout: K buf0 @0, K buf1 @8192, V buf0 @16384, V buf1 @24576 (each 64 rows x 128B, swizzled)
  const int q0 = blockIdx.x * 64;
  const int bh = blockIdx.y, b = bh >> 4, h = bh & 15;
  const int t = threadIdx.x, w = t >> 6, l = t & 63;
  const int lr = l & 15, lg = l >> 4;
  const bool useMask = (flag[0] != 0);
  const int qrow = q0 + w * 16 + lr;           // this lane's q row

  // Q fragments (B operand): 2 x 16B direct from global, constant over KV loop
  const u16* qp = Qb + (size_t)(b * SEQ_LEN + qrow) * HID + h * HDIM;
  bf16x8 qf[2];
#pragma unroll
  for (int ks = 0; ks < 2; ks++) qf[ks] = *(const bf16x8*)(qp + (ks * 4 + lg) * 8);

  f32x4 oacc[4];   // O^T fragments: oacc[dt][i] = O[qrow][dt*16+lg*4+i]
#pragma unroll
  for (int dt = 0; dt < 4; dt++) oacc[dt] = (f32x4){0.f, 0.f, 0.f, 0.f};
  float m_r = -1e30f, l_r = 0.f;

  const size_t kbase = (size_t)(b * SEQ_LEN) * HID + h * HDIM;
  const size_t vbase = ((size_t)(b * NHEAD + h) * HDIM) * SEQ_LEN;

  // stage tile kv0 into buffer bi
  auto stage = [&](int bi, int kv0) {
#pragma unroll
    for (int j = 0; j < 2; j++) {
      int o = w * 2048 + j * 1024 + l * 16;
      int row = o >> 7, kb = (o >> 4) & 7, skb = kb ^ (row & 7);
      gload16(Kb + kbase + (size_t)(kv0 + row) * HID + skb * 8, lds + bi * 8192 + o);
      gload16(VT + vbase + (size_t)row * SEQ_LEN + kv0 + skb * 8, lds + 16384 + bi * 8192 + o);
    }
  };

  stage(0, 0);
  __syncthreads();

  const int NT = SEQ_LEN / 64;
  for (int tIt = 0; tIt < NT; ++tIt) {
    int cur = tIt & 1;
    if (tIt + 1 < NT) stage(cur ^ 1, (tIt + 1) * 64);
    char* Ks = lds + cur * 8192;
    char* Vs = lds + 16384 + cur * 8192;

    // S^T = K . Q^T : sf[kt][i] = S[q=lr][k=kt*16+lg*4+i] (already x log2e/8)
    f32x4 sf[4];
#pragma unroll
    for (int kt = 0; kt < 4; kt++) sf[kt] = (f32x4){0.f, 0.f, 0.f, 0.f};
#pragma unroll
    for (int ks = 0; ks < 2; ks++) {
      int kb = ks * 4 + lg;
#pragma unroll
      for (int kt = 0; kt < 4; kt++) {
        int krow = kt * 16 + lr;
        bf16x8 kf = *(const bf16x8*)(Ks + krow * 128 + ((kb ^ (krow & 7)) << 4));
        sf[kt] = __builtin_amdgcn_mfma_f32_16x16x32_bf16(kf, qf[ks], sf[kt], 0, 0, 0);
      }
    }

    if (useMask) {  // slow path (benchmark mask is all-zero); S is in log2 domain
      int kv0 = tIt * 64;
#pragma unroll
      for (int kt = 0; kt < 4; kt++)
#pragma unroll
        for (int i = 0; i < 4; i++)
          sf[kt][i] += mask[(size_t)qrow * SEQ_LEN + kv0 + kt * 16 + lg * 4 + i] * LOG2E;
    }

    // online softmax (base-2), lane-local row + 2 shuffles across lg groups
    float mx = fmaxf(fmaxf(fmaxf(sf[0][0], sf[0][1]), fmaxf(sf[0][2], sf[0][3])),
                     fmaxf(fmaxf(sf[1][0], sf[1][1]), fmaxf(sf[1][2], sf[1][3])));
    mx = fmaxf(mx, fmaxf(fmaxf(fmaxf(sf[2][0], sf[2][1]), fmaxf(sf[2][2], sf[2][3])),
                         fmaxf(fmaxf(sf[3][0], sf[3][1]), fmaxf(sf[3][2], sf[3][3]))));
    mx = fmaxf(mx, __shfl_xor(mx, 16));
    mx = fmaxf(mx, __shfl_xor(mx, 32));
    float nm = fmaxf(m_r, mx);
    float scf = exp2f(m_r - nm);
    m_r = nm;
    float s = 0.f;
#pragma unroll
    for (int kt = 0; kt < 4; kt++)
#pragma unroll
      for (int i = 0; i < 4; i++) {
        float p = exp2f(sf[kt][i] - nm);
        sf[kt][i] = p;
        s += p;
      }
    s += __shfl_xor(s, 16);
    s += __shfl_xor(s, 32);
    l_r = l_r * scf + s;
#pragma unroll
    for (int dt = 0; dt < 4; dt++)
#pragma unroll
      for (int i = 0; i < 4; i++) oacc[dt][i] *= scf;

    // O^T += V^T . P^T   (P^T from regs as B operand; V^T A operand uses matching k-map:
    //  slot(lg,j) -> k = (2ks + (j>>2))*16 + lg*4 + (j&3))
#pragma unroll
    for (int ks = 0; ks < 2; ks++) {
      bf16x8 pb;
#pragma unroll
      for (int j = 0; j < 4; j++) pb[j] = (__bf16)sf[2 * ks][j];
#pragma unroll
      for (int j = 0; j < 4; j++) pb[4 + j] = (__bf16)sf[2 * ks + 1][j];
      int kb0 = 4 * ks + (lg >> 1);
      int wb = (lg & 1) * 8;
#pragma unroll
      for (int dt = 0; dt < 4; dt++) {
        int vrow = dt * 16 + lr;
        const char* vb = Vs + vrow * 128;
        bf16x4 vlo = *(const bf16x4*)(vb + ((kb0 ^ (vrow & 7)) << 4) + wb);
        bf16x4 vhi = *(const bf16x4*)(vb + (((kb0 + 2) ^ (vrow & 7)) << 4) + wb);
        bf16x8 vf = __builtin_shufflevector(vlo, vhi, 0, 1, 2, 3, 4, 5, 6, 7);
        oacc[dt] = __builtin_amdgcn_mfma_f32_16x16x32_bf16(vf, pb, oacc[dt], 0, 0, 0);
      }
    }
    __syncthreads();   // staged next tile landed; all waves done with cur
  }

  // epilogue: normalize, pack 4 consecutive d per store
  float inv = 1.f / l_r;
  u16* orow = Ob + (size_t)(b * SEQ_LEN + qrow) * HID + h * HDIM;
#pragma unroll
  for (int dt = 0; dt < 4; dt++) {
    ushort4 pk = make_ushort4(f2bf(oacc[dt][0] * inv), f2bf(oacc[dt][1] * inv),
                              f2bf(oacc[dt][2] * inv), f2bf(oacc[dt][3] * inv));
    *(ushort4*)(orow + dt * 16 + lg * 4) = pk;
  }
}

// ---------------- launch ----------------

extern "C" void kernel_launch(void* const* d_in, const int* in_sizes, int n_in,
                              void* d_out, int out_size, void* d_ws, size_t ws_size,
                              hipStream_t stream) {
  const float* x    = (const float*)d_in[0];
  const float* mask = (const float*)d_in[1];
  const float* wq   = (const float*)d_in[2];
  const float* bq   = (const float*)d_in[3];
  const float* wk   = (const float*)d_in[4];
  const float* bk   = (const float*)d_in[5];
  const float* wv   = (const float*)d_in[6];
  const float* bv   = (const float*)d_in[7];
  const float* wo   = (const float*)d_in[8];
  const float* bo   = (const float*)d_in[9];

  char* ws = (char*)d_ws;
  u16* xb  = (u16*)(ws + 0);          // 16 MB (reused as Ob after QKV GEMM)
  u16* wqb = (u16*)(ws + 16777216);   // 2 MB each
  u16* wkb = (u16*)(ws + 18874368);
  u16* wvb = (u16*)(ws + 20971520);
  u16* wob = (u16*)(ws + 23068672);
  u16* Qb  = (u16*)(ws + 25165824);   // 16 MB
  u16* Kb  = (u16*)(ws + 41943040);   // 16 MB
  u16* VT  = (u16*)(ws + 58720256);   // 16 MB
  int* flag = (int*)(ws + 75497472);
  u16* Ob = xb;

  (void)hipMemsetAsync(flag, 0, 4, stream);
  cvt_x_kernel<<<2048, 256, 0, stream>>>(x, xb, MROWS * HID / 4);
  cvt_w_kernel<<<dim3(1024, 4), 256, 0, stream>>>(wq, wk, wv, wo, wqb);
  maskchk_kernel<<<2048, 256, 0, stream>>>(mask, SEQ_LEN * SEQ_LEN / 4, flag);
  gemm_qkv_kernel<<<dim3(64, 24), 256, 0, stream>>>(xb, wqb, wkb, wvb, bq, bk, bv, Qb, Kb, VT);
  attn_kernel<<<dim3(64, 32), 256, 0, stream>>>(Qb, Kb, VT, mask, flag, Ob);
  gemm_out_kernel<<<dim3(64, 8), 256, 0, stream>>>(Ob, wob, bo, (float*)d_out);
}

// Round 4
// 372.969 us; speedup vs baseline: 1.4605x; 1.1389x over previous
//
#include <hip/hip_runtime.h>

typedef unsigned short u16;
typedef __bf16 bf16x4 __attribute__((ext_vector_type(4)));
typedef __bf16 bf16x8 __attribute__((ext_vector_type(8)));
typedef float f32x4 __attribute__((ext_vector_type(4)));

#define SEQ_LEN 4096
#define HID 1024
#define NHEAD 16
#define HDIM 64
#define MROWS 8192   // B*S
#define LOG2E 1.44269504088896f

__device__ __forceinline__ u16 f2bf(float f) {
  union { float f; unsigned u; } v; v.f = f;
  unsigned r = v.u + 0x7fffu + ((v.u >> 16) & 1u);
  return (u16)(r >> 16);
}

__device__ __forceinline__ void gload16(const void* g, void* lds) {
  __builtin_amdgcn_global_load_lds((const __attribute__((address_space(1))) void*)g,
                                   (__attribute__((address_space(3))) void*)lds, 16, 0, 0);
}

// ---------------- conversion kernels ----------------

__global__ void cvt_x_kernel(const float* __restrict__ src, u16* __restrict__ dst, int n4) {
  int stride = gridDim.x * blockDim.x;
  for (int i = blockIdx.x * blockDim.x + threadIdx.x; i < n4; i += stride) {
    float4 v = ((const float4*)src)[i];
    ((ushort4*)dst)[i] = make_ushort4(f2bf(v.x), f2bf(v.y), f2bf(v.z), f2bf(v.w));
  }
}

__global__ void cvt_w_kernel(const float* __restrict__ w0, const float* __restrict__ w1,
                             const float* __restrict__ w2, const float* __restrict__ w3,
                             u16* __restrict__ dst) {
  const float* src = (blockIdx.y == 0) ? w0 : (blockIdx.y == 1) ? w1 : (blockIdx.y == 2) ? w2 : w3;
  u16* d = dst + (size_t)blockIdx.y * (HID * HID);
  int i = blockIdx.x * blockDim.x + threadIdx.x;
  float4 v = ((const float4*)src)[i];
  ((ushort4*)d)[i] = make_ushort4(f2bf(v.x), f2bf(v.y), f2bf(v.z), f2bf(v.w));
}

__global__ void maskchk_kernel(const float* __restrict__ mask, int n4, int* flag) {
  int stride = gridDim.x * blockDim.x;
  bool nz = false;
  for (int i = blockIdx.x * blockDim.x + threadIdx.x; i < n4; i += stride) {
    float4 v = ((const float4*)mask)[i];
    nz |= (v.x != 0.f) | (v.y != 0.f) | (v.z != 0.f) | (v.w != 0.f);
  }
  if (__any(nz) && (threadIdx.x & 63) == 0) atomicOr(flag, 1);
}

// ---------------- GEMM core (y = A @ W^T), 128x128 tile, BK=64 ----------------

__device__ __forceinline__ void gemm_core(const u16* __restrict__ A, const u16* __restrict__ W,
                                          int m0, int n0, char* As, char* Bs, f32x4 acc[4][4]) {
  const int t = threadIdx.x, w = t >> 6, l = t & 63;
  const int lr = l & 15, lg = l >> 4;
  const int wr = (w >> 1) * 64, wc = (w & 1) * 64;
#pragma unroll
  for (int i = 0; i < 4; i++)
#pragma unroll
    for (int j = 0; j < 4; j++) acc[i][j] = (f32x4){0.f, 0.f, 0.f, 0.f};

  for (int k0 = 0; k0 < HID; k0 += 64) {
    __syncthreads();
#pragma unroll
    for (int j = 0; j < 4; j++) {
      int o = w * 4096 + j * 1024 + l * 16;
      int row = o >> 7, kb = (o >> 4) & 7, skb = kb ^ (row & 7);
      gload16(A + (size_t)(m0 + row) * HID + k0 + skb * 8, As + (w * 4096 + j * 1024));
      gload16(W + (size_t)(n0 + row) * HID + k0 + skb * 8, Bs + (w * 4096 + j * 1024));
    }
    __syncthreads();
#pragma unroll
    for (int ks = 0; ks < 2; ks++) {
      bf16x8 af[4], bf[4];
      int kb = ks * 4 + lg;
#pragma unroll
      for (int mt = 0; mt < 4; mt++) {
        int row = wr + mt * 16 + lr;
        af[mt] = *(const bf16x8*)(As + row * 128 + ((kb ^ (row & 7)) << 4));
      }
#pragma unroll
      for (int nt = 0; nt < 4; nt++) {
        int row = wc + nt * 16 + lr;
        bf[nt] = *(const bf16x8*)(Bs + row * 128 + ((kb ^ (row & 7)) << 4));
      }
#pragma unroll
      for (int mt = 0; mt < 4; mt++)
#pragma unroll
        for (int nt = 0; nt < 4; nt++)
          acc[mt][nt] = __builtin_amdgcn_mfma_f32_16x16x32_bf16(af[mt], bf[nt], acc[mt][nt], 0, 0, 0);
    }
  }
}

// QKV GEMM: gridDim = (64, 24). mat 0=Q (prescale log2e/8), 1=K, 2=V (transposed+permuted store)
__global__ __launch_bounds__(256) void gemm_qkv_kernel(
    const u16* __restrict__ xb, const u16* __restrict__ wqb, const u16* __restrict__ wkb,
    const u16* __restrict__ wvb, const float* __restrict__ bq, const float* __restrict__ bk,
    const float* __restrict__ bv, u16* __restrict__ Qb, u16* __restrict__ Kb, u16* __restrict__ VT) {
  __shared__ __align__(128) char lds[32768];
  int m0 = blockIdx.x * 128;
  int ng = blockIdx.y * 128;
  int mat = ng >> 10, n0 = ng & 1023;
  const u16* W = (mat == 0) ? wqb : (mat == 1) ? wkb : wvb;
  const float* bias = (mat == 0) ? bq : (mat == 1) ? bk : bv;
  f32x4 acc[4][4];
  gemm_core(xb, W, m0, n0, lds, lds + 16384, acc);

  const int t = threadIdx.x, w = t >> 6, l = t & 63;
  const int lr = l & 15, lg = l >> 4;
  if (mat < 2) {
    u16* dst = (mat == 0) ? Qb : Kb;
    float scale = (mat == 0) ? 0.125f * LOG2E : 1.0f;
#pragma unroll
    for (int mt = 0; mt < 4; mt++)
#pragma unroll
      for (int nt = 0; nt < 4; nt++) {
        int n = n0 + (w & 1) * 64 + nt * 16 + lr;
        float bn = bias[n];
#pragma unroll
        for (int i = 0; i < 4; i++) {
          int m = m0 + (w >> 1) * 64 + mt * 16 + lg * 4 + i;
          dst[(size_t)m * HID + n] = f2bf((acc[mt][nt][i] + bn) * scale);
        }
      }
  } else {
#pragma unroll
    for (int mt = 0; mt < 4; mt++)
#pragma unroll
      for (int nt = 0; nt < 4; nt++) {
        int m = m0 + (w >> 1) * 64 + mt * 16 + lg * 4;  // s base (4 consecutive, 4-aligned)
        int n = n0 + (w & 1) * 64 + nt * 16 + lr;       // d-global
        int b = m >> 12, s = m & 4095;
        int h = n >> 6, d = n & 63;
        // permute s within its 64-block so attn PV reads one 16B block per lane:
        // 4-run index t4 = (ks<<3)|(h1<<2)|lg2  ->  t4' = (ks<<3)|(lg2<<1)|h1
        int t4 = (s >> 2) & 15;
        int t4p = ((t4 & 8)) | ((t4 & 3) << 1) | ((t4 >> 2) & 1);
        int sp = (s & ~63) | (t4p << 2);
        float bn = bias[n];
        ushort4 pk = make_ushort4(f2bf(acc[mt][nt][0] + bn), f2bf(acc[mt][nt][1] + bn),
                                  f2bf(acc[mt][nt][2] + bn), f2bf(acc[mt][nt][3] + bn));
        *(ushort4*)(VT + (((size_t)(b * NHEAD + h) * HDIM + d) * SEQ_LEN + sp)) = pk;
      }
  }
}

// out-proj GEMM: gridDim = (64, 8), fp32 output + bias
__global__ __launch_bounds__(256) void gemm_out_kernel(
    const u16* __restrict__ Ob, const u16* __restrict__ wob, const float* __restrict__ bo,
    float* __restrict__ out) {
  __shared__ __align__(128) char lds[32768];
  int m0 = blockIdx.x * 128, n0 = blockIdx.y * 128;
  f32x4 acc[4][4];
  gemm_core(Ob, wob, m0, n0, lds, lds + 16384, acc);
  const int t = threadIdx.x, w = t >> 6, l = t & 63;
  const int lr = l & 15, lg = l >> 4;
#pragma unroll
  for (int mt = 0; mt < 4; mt++)
#pragma unroll
    for (int nt = 0; nt < 4; nt++) {
      int n = n0 + (w & 1) * 64 + nt * 16 + lr;
      float bn = bo[n];
#pragma unroll
      for (int i = 0; i < 4; i++) {
        int m = m0 + (w >> 1) * 64 + mt * 16 + lg * 4 + i;
        out[(size_t)m * HID + n] = acc[mt][nt][i] + bn;
      }
    }
}

// ---------------- flash attention (swapped QK^T, in-register softmax) ----------------
// grid = (64, 32). S^T = K.Q^T so each lane owns one q-row; P in registers; l via MFMA
// ones-trick; defer-max rescale (THR=8).
__global__ __launch_bounds__(256) void attn_kernel(
    const u16* __restrict__ Qb, const u16* __restrict__ Kb, const u16* __restrict__ VT,
    const float* __restrict__ mask, const int* __restrict__ flag, u16* __restrict__ Ob) {
  __shared__ __align__(128) char lds[32768];
  // K buf0 @0, K buf1 @8192, V buf0 @16384, V buf1 @24576 (64 rows x 128B, swizzled)
  const int q0 = blockIdx.x * 64;
  const int bh = blockIdx.y, b = bh >> 4, h = bh & 15;
  const int t = threadIdx.x, w = t >> 6, l = t & 63;
  const int lr = l & 15, lg = l >> 4;
  const bool useMask = (flag[0] != 0);
  const int qrow = q0 + w * 16 + lr;

  const u16* qp = Qb + (size_t)(b * SEQ_LEN + qrow) * HID + h * HDIM;
  bf16x8 qf[2];
#pragma unroll
  for (int ks = 0; ks < 2; ks++) qf[ks] = *(const bf16x8*)(qp + (ks * 4 + lg) * 8);

  bf16x8 ones;
#pragma unroll
  for (int j = 0; j < 8; j++) ones[j] = (__bf16)1.0f;

  f32x4 oacc[4];   // oacc[dt][i] = O[qrow][dt*16+lg*4+i]
#pragma unroll
  for (int dt = 0; dt < 4; dt++) oacc[dt] = (f32x4){0.f, 0.f, 0.f, 0.f};
  f32x4 lacc = (f32x4){0.f, 0.f, 0.f, 0.f};   // all 4 entries = running l for q=lr
  float m_r = -1e30f;

  const size_t kbase = (size_t)(b * SEQ_LEN) * HID + h * HDIM;
  const size_t vbase = ((size_t)(b * NHEAD + h) * HDIM) * SEQ_LEN;

  auto stage = [&](int bi, int kv0) {
#pragma unroll
    for (int j = 0; j < 2; j++) {
      int o = w * 2048 + j * 1024 + l * 16;
      int row = o >> 7, kb = (o >> 4) & 7, skb = kb ^ (row & 7);
      gload16(Kb + kbase + (size_t)(kv0 + row) * HID + skb * 8, lds + bi * 8192 + o);
      gload16(VT + vbase + (size_t)row * SEQ_LEN + kv0 + skb * 8, lds + 16384 + bi * 8192 + o);
    }
  };

  stage(0, 0);
  __syncthreads();

  const int NT = SEQ_LEN / 64;
  for (int tIt = 0; tIt < NT; ++tIt) {
    int cur = tIt & 1;
    if (tIt + 1 < NT) stage(cur ^ 1, (tIt + 1) * 64);
    char* Ks = lds + cur * 8192;
    char* Vs = lds + 16384 + cur * 8192;

    // S^T = K . Q^T : sf[kt][i] = S[q=lr][k=kt*16+lg*4+i]  (already x log2e/8)
    f32x4 sf[4];
#pragma unroll
    for (int kt = 0; kt < 4; kt++) sf[kt] = (f32x4){0.f, 0.f, 0.f, 0.f};
#pragma unroll
    for (int ks = 0; ks < 2; ks++) {
      int kb = ks * 4 + lg;
#pragma unroll
      for (int kt = 0; kt < 4; kt++) {
        int krow = kt * 16 + lr;
        bf16x8 kf = *(const bf16x8*)(Ks + krow * 128 + ((kb ^ (krow & 7)) << 4));
        sf[kt] = __builtin_amdgcn_mfma_f32_16x16x32_bf16(kf, qf[ks], sf[kt], 0, 0, 0);
      }
    }

    if (useMask) {  // slow path (benchmark mask all-zero); S in log2 domain
      int kv0 = tIt * 64;
#pragma unroll
      for (int kt = 0; kt < 4; kt++)
#pragma unroll
        for (int i = 0; i < 4; i++)
          sf[kt][i] += mask[(size_t)qrow * SEQ_LEN + kv0 + kt * 16 + lg * 4 + i] * LOG2E;
    }

    // tile max for this q-row (lane-local 16 + 2 shuffles)
    float mx = fmaxf(fmaxf(fmaxf(sf[0][0], sf[0][1]), fmaxf(sf[0][2], sf[0][3])),
                     fmaxf(fmaxf(sf[1][0], sf[1][1]), fmaxf(sf[1][2], sf[1][3])));
    mx = fmaxf(mx, fmaxf(fmaxf(fmaxf(sf[2][0], sf[2][1]), fmaxf(sf[2][2], sf[2][3])),
                         fmaxf(fmaxf(sf[3][0], sf[3][1]), fmaxf(sf[3][2], sf[3][3]))));
    mx = fmaxf(mx, __shfl_xor(mx, 16));
    mx = fmaxf(mx, __shfl_xor(mx, 32));

    // defer-max: only rescale when tile max exceeds running max by >8 (P bounded by 2^8)
    if (__any(mx > m_r + 8.0f)) {
      float nm = fmaxf(m_r, mx);
      float scf = exp2f(m_r - nm);
      m_r = nm;
#pragma unroll
      for (int dt = 0; dt < 4; dt++)
#pragma unroll
        for (int i = 0; i < 4; i++) oacc[dt][i] *= scf;
      lacc *= scf;
    }

#pragma unroll
    for (int kt = 0; kt < 4; kt++)
#pragma unroll
      for (int i = 0; i < 4; i++) sf[kt][i] = exp2f(sf[kt][i] - m_r);

    // O^T += V^T . P^T ; l += 1 . P^T  (V pre-permuted so one b128 per fragment)
#pragma unroll
    for (int ks = 0; ks < 2; ks++) {
      bf16x8 pb;
#pragma unroll
      for (int j = 0; j < 4; j++) pb[j] = (__bf16)sf[2 * ks][j];
#pragma unroll
      for (int j = 0; j < 4; j++) pb[4 + j] = (__bf16)sf[2 * ks + 1][j];
      int kb = ks * 4 + lg;
#pragma unroll
      for (int dt = 0; dt < 4; dt++) {
        int vrow = dt * 16 + lr;
        bf16x8 vf = *(const bf16x8*)(Vs + vrow * 128 + ((kb ^ (vrow & 7)) << 4));
        oacc[dt] = __builtin_amdgcn_mfma_f32_16x16x32_bf16(vf, pb, oacc[dt], 0, 0, 0);
      }
      lacc = __builtin_amdgcn_mfma_f32_16x16x32_bf16(ones, pb, lacc, 0, 0, 0);
    }
    __syncthreads();   // staged next tile landed; all waves done with cur
  }

  // epilogue: normalize, pack 4 consecutive d per store
  float inv = 1.0f / lacc[0];
  u16* orow = Ob + (size_t)(b * SEQ_LEN + qrow) * HID + h * HDIM;
#pragma unroll
  for (int dt = 0; dt < 4; dt++) {
    ushort4 pk = make_ushort4(f2bf(oacc[dt][0] * inv), f2bf(oacc[dt][1] * inv),
                              f2bf(oacc[dt][2] * inv), f2bf(oacc[dt][3] * inv));
    *(ushort4*)(orow + dt * 16 + lg * 4) = pk;
  }
}

// ---------------- launch ----------------

extern "C" void kernel_launch(void* const* d_in, const int* in_sizes, int n_in,
                              void* d_out, int out_size, void* d_ws, size_t ws_size,
                              hipStream_t stream) {
  const float* x    = (const float*)d_in[0];
  const float* mask = (const float*)d_in[1];
  const float* wq   = (const float*)d_in[2];
  const float* bq   = (const float*)d_in[3];
  const float* wk   = (const float*)d_in[4];
  const float* bk   = (const float*)d_in[5];
  const float* wv   = (const float*)d_in[6];
  const float* bv   = (const float*)d_in[7];
  const float* wo   = (const float*)d_in[8];
  const float* bo   = (const float*)d_in[9];

  char* ws = (char*)d_ws;
  u16* xb  = (u16*)(ws + 0);          // 16 MB (reused as Ob after QKV GEMM)
  u16* wqb = (u16*)(ws + 16777216);   // 2 MB each
  u16* wkb = (u16*)(ws + 18874368);
  u16* wvb = (u16*)(ws + 20971520);
  u16* wob = (u16*)(ws + 23068672);
  u16* Qb  = (u16*)(ws + 25165824);   // 16 MB
  u16* Kb  = (u16*)(ws + 41943040);   // 16 MB
  u16* VT  = (u16*)(ws + 58720256);   // 16 MB
  int* flag = (int*)(ws + 75497472);
  u16* Ob = xb;

  (void)hipMemsetAsync(flag, 0, 4, stream);
  cvt_x_kernel<<<2048, 256, 0, stream>>>(x, xb, MROWS * HID / 4);
  cvt_w_kernel<<<dim3(1024, 4), 256, 0, stream>>>(wq, wk, wv, wo, wqb);
  maskchk_kernel<<<2048, 256, 0, stream>>>(mask, SEQ_LEN * SEQ_LEN / 4, flag);
  gemm_qkv_kernel<<<dim3(64, 24), 256, 0, stream>>>(xb, wqb, wkb, wvb, bq, bk, bv, Qb, Kb, VT);
  attn_kernel<<<dim3(64, 32), 256, 0, stream>>>(Qb, Kb, VT, mask, flag, Ob);
  gemm_out_kernel<<<dim3(64, 8), 256, 0, stream>>>(Ob, wob, bo, (float*)d_out);
}

// Round 5
// 345.645 us; speedup vs baseline: 1.5760x; 1.0791x over previous
//
#include <hip/hip_runtime.h>

typedef unsigned short u16;
typedef __bf16 bf16x4 __attribute__((ext_vector_type(4)));
typedef __bf16 bf16x8 __attribute__((ext_vector_type(8)));
typedef float f32x4 __attribute__((ext_vector_type(4)));

#define SEQ_LEN 4096
#define HID 1024
#define NHEAD 16
#define HDIM 64
#define MROWS 8192   // B*S
#define LOG2E 1.44269504088896f

__device__ __forceinline__ u16 f2bf(float f) {
  union { float f; unsigned u; } v; v.f = f;
  unsigned r = v.u + 0x7fffu + ((v.u >> 16) & 1u);
  return (u16)(r >> 16);
}

__device__ __forceinline__ void gload16(const void* g, void* lds) {
  __builtin_amdgcn_global_load_lds((const __attribute__((address_space(1))) void*)g,
                                   (__attribute__((address_space(3))) void*)lds, 16, 0, 0);
}

// ---------------- conversion kernels ----------------

__global__ void cvt_x_kernel(const float* __restrict__ src, u16* __restrict__ dst, int n4) {
  int stride = gridDim.x * blockDim.x;
  for (int i = blockIdx.x * blockDim.x + threadIdx.x; i < n4; i += stride) {
    float4 v = ((const float4*)src)[i];
    ((ushort4*)dst)[i] = make_ushort4(f2bf(v.x), f2bf(v.y), f2bf(v.z), f2bf(v.w));
  }
}

__global__ void cvt_w_kernel(const float* __restrict__ w0, const float* __restrict__ w1,
                             const float* __restrict__ w2, const float* __restrict__ w3,
                             u16* __restrict__ dst) {
  const float* src = (blockIdx.y == 0) ? w0 : (blockIdx.y == 1) ? w1 : (blockIdx.y == 2) ? w2 : w3;
  u16* d = dst + (size_t)blockIdx.y * (HID * HID);
  int i = blockIdx.x * blockDim.x + threadIdx.x;
  float4 v = ((const float4*)src)[i];
  ((ushort4*)d)[i] = make_ushort4(f2bf(v.x), f2bf(v.y), f2bf(v.z), f2bf(v.w));
}

__global__ void maskchk_kernel(const float* __restrict__ mask, int n4, int* flag) {
  int stride = gridDim.x * blockDim.x;
  bool nz = false;
  for (int i = blockIdx.x * blockDim.x + threadIdx.x; i < n4; i += stride) {
    float4 v = ((const float4*)mask)[i];
    nz |= (v.x != 0.f) | (v.y != 0.f) | (v.z != 0.f) | (v.w != 0.f);
  }
  if (__any(nz) && (threadIdx.x & 63) == 0) atomicOr(flag, 1);
}

// ---------------- GEMM core (y = A @ W^T), 128x128 tile, BK=64 ----------------

__device__ __forceinline__ void gemm_core(const u16* __restrict__ A, const u16* __restrict__ W,
                                          int m0, int n0, char* As, char* Bs, f32x4 acc[4][4]) {
  const int t = threadIdx.x, w = t >> 6, l = t & 63;
  const int lr = l & 15, lg = l >> 4;
  const int wr = (w >> 1) * 64, wc = (w & 1) * 64;
#pragma unroll
  for (int i = 0; i < 4; i++)
#pragma unroll
    for (int j = 0; j < 4; j++) acc[i][j] = (f32x4){0.f, 0.f, 0.f, 0.f};

  for (int k0 = 0; k0 < HID; k0 += 64) {
    __syncthreads();
#pragma unroll
    for (int j = 0; j < 4; j++) {
      int o = w * 4096 + j * 1024 + l * 16;
      int row = o >> 7, kb = (o >> 4) & 7, skb = kb ^ (row & 7);
      gload16(A + (size_t)(m0 + row) * HID + k0 + skb * 8, As + (w * 4096 + j * 1024));
      gload16(W + (size_t)(n0 + row) * HID + k0 + skb * 8, Bs + (w * 4096 + j * 1024));
    }
    __syncthreads();
#pragma unroll
    for (int ks = 0; ks < 2; ks++) {
      bf16x8 af[4], bf[4];
      int kb = ks * 4 + lg;
#pragma unroll
      for (int mt = 0; mt < 4; mt++) {
        int row = wr + mt * 16 + lr;
        af[mt] = *(const bf16x8*)(As + row * 128 + ((kb ^ (row & 7)) << 4));
      }
#pragma unroll
      for (int nt = 0; nt < 4; nt++) {
        int row = wc + nt * 16 + lr;
        bf[nt] = *(const bf16x8*)(Bs + row * 128 + ((kb ^ (row & 7)) << 4));
      }
#pragma unroll
      for (int mt = 0; mt < 4; mt++)
#pragma unroll
        for (int nt = 0; nt < 4; nt++)
          acc[mt][nt] = __builtin_amdgcn_mfma_f32_16x16x32_bf16(af[mt], bf[nt], acc[mt][nt], 0, 0, 0);
    }
  }
}

// QKV GEMM: gridDim = (64, 24). mat 0=Q (prescale log2e/8), 1=K, 2=V (transposed+permuted store)
__global__ __launch_bounds__(256) void gemm_qkv_kernel(
    const u16* __restrict__ xb, const u16* __restrict__ wqb, const u16* __restrict__ wkb,
    const u16* __restrict__ wvb, const float* __restrict__ bq, const float* __restrict__ bk,
    const float* __restrict__ bv, u16* __restrict__ Qb, u16* __restrict__ Kb, u16* __restrict__ VT) {
  __shared__ __align__(128) char lds[32768];
  int m0 = blockIdx.x * 128;
  int ng = blockIdx.y * 128;
  int mat = ng >> 10, n0 = ng & 1023;
  const u16* W = (mat == 0) ? wqb : (mat == 1) ? wkb : wvb;
  const float* bias = (mat == 0) ? bq : (mat == 1) ? bk : bv;
  f32x4 acc[4][4];
  gemm_core(xb, W, m0, n0, lds, lds + 16384, acc);

  const int t = threadIdx.x, w = t >> 6, l = t & 63;
  const int lr = l & 15, lg = l >> 4;
  if (mat < 2) {
    u16* dst = (mat == 0) ? Qb : Kb;
    float scale = (mat == 0) ? 0.125f * LOG2E : 1.0f;
#pragma unroll
    for (int mt = 0; mt < 4; mt++)
#pragma unroll
      for (int nt = 0; nt < 4; nt++) {
        int n = n0 + (w & 1) * 64 + nt * 16 + lr;
        float bn = bias[n];
#pragma unroll
        for (int i = 0; i < 4; i++) {
          int m = m0 + (w >> 1) * 64 + mt * 16 + lg * 4 + i;
          dst[(size_t)m * HID + n] = f2bf((acc[mt][nt][i] + bn) * scale);
        }
      }
  } else {
#pragma unroll
    for (int mt = 0; mt < 4; mt++)
#pragma unroll
      for (int nt = 0; nt < 4; nt++) {
        int m = m0 + (w >> 1) * 64 + mt * 16 + lg * 4;  // s base (4 consecutive, 4-aligned)
        int n = n0 + (w & 1) * 64 + nt * 16 + lr;       // d-global
        int b = m >> 12, s = m & 4095;
        int h = n >> 6, d = n & 63;
        // permute s within its 64-block so attn PV reads one 16B block per lane
        int t4 = (s >> 2) & 15;
        int t4p = ((t4 & 8)) | ((t4 & 3) << 1) | ((t4 >> 2) & 1);
        int sp = (s & ~63) | (t4p << 2);
        float bn = bias[n];
        ushort4 pk = make_ushort4(f2bf(acc[mt][nt][0] + bn), f2bf(acc[mt][nt][1] + bn),
                                  f2bf(acc[mt][nt][2] + bn), f2bf(acc[mt][nt][3] + bn));
        *(ushort4*)(VT + (((size_t)(b * NHEAD + h) * HDIM + d) * SEQ_LEN + sp)) = pk;
      }
  }
}

// out-proj GEMM: gridDim = (64, 8), fp32 output + bias
__global__ __launch_bounds__(256) void gemm_out_kernel(
    const u16* __restrict__ Ob, const u16* __restrict__ wob, const float* __restrict__ bo,
    float* __restrict__ out) {
  __shared__ __align__(128) char lds[32768];
  int m0 = blockIdx.x * 128, n0 = blockIdx.y * 128;
  f32x4 acc[4][4];
  gemm_core(Ob, wob, m0, n0, lds, lds + 16384, acc);
  const int t = threadIdx.x, w = t >> 6, l = t & 63;
  const int lr = l & 15, lg = l >> 4;
#pragma unroll
  for (int mt = 0; mt < 4; mt++)
#pragma unroll
    for (int nt = 0; nt < 4; nt++) {
      int n = n0 + (w & 1) * 64 + nt * 16 + lr;
      float bn = bo[n];
#pragma unroll
      for (int i = 0; i < 4; i++) {
        int m = m0 + (w >> 1) * 64 + mt * 16 + lg * 4 + i;
        out[(size_t)m * HID + n] = acc[mt][nt][i] + bn;
      }
    }
}

// ---------------- flash attention ----------------
// grid = (64, 32). S^T = K.Q^T; P in registers; l via MFMA ones-trick; defer-max.
// KV loop unrolled x2 (compile-time buffer index); LDS offsets precomputed per lane;
// staging pointers advanced by constant strides.
__global__ __launch_bounds__(256, 2) void attn_kernel(
    const u16* __restrict__ Qb, const u16* __restrict__ Kb, const u16* __restrict__ VT,
    const float* __restrict__ mask, const int* __restrict__ flag, u16* __restrict__ Ob) {
  __shared__ __align__(128) char lds[32768];
  // K buf0 @0, K buf1 @8192, V buf0 @16384, V buf1 @24576 (64 rows x 128B, swizzled)
  const int q0 = blockIdx.x * 64;
  const int bh = blockIdx.y, b = bh >> 4, h = bh & 15;
  const int t = threadIdx.x, w = t >> 6, l = t & 63;
  const int lr = l & 15, lg = l >> 4;
  const bool useMask = (flag[0] != 0);
  const int qrow = q0 + w * 16 + lr;

  const u16* qp = Qb + (size_t)(b * SEQ_LEN + qrow) * HID + h * HDIM;
  bf16x8 qf[2];
#pragma unroll
  for (int ks = 0; ks < 2; ks++) qf[ks] = *(const bf16x8*)(qp + (ks * 4 + lg) * 8);

  bf16x8 ones;
#pragma unroll
  for (int j = 0; j < 8; j++) ones[j] = (__bf16)1.0f;

  f32x4 oacc[4];
#pragma unroll
  for (int dt = 0; dt < 4; dt++) oacc[dt] = (f32x4){0.f, 0.f, 0.f, 0.f};
  f32x4 lacc = (f32x4){0.f, 0.f, 0.f, 0.f};
  float m_r = -1e30f;

  // lane-constant swizzled LDS read offsets (shared by K and V reads: row = idx*16+lr)
  int off[2][4];
#pragma unroll
  for (int ks = 0; ks < 2; ks++) {
    int kb = ks * 4 + lg;
#pragma unroll
    for (int kt = 0; kt < 4; kt++) {
      int row = kt * 16 + lr;
      off[ks][kt] = row * 128 + ((kb ^ (row & 7)) << 4);
    }
  }

  // staging: lane-constant LDS dest offsets + global pointers advanced by constants
  const int o0 = w * 2048 + l * 16;
  const int o1 = o0 + 1024;
  const int r0 = o0 >> 7, r1 = o1 >> 7;
  const int sk0 = ((o0 >> 4) & 7) ^ (r0 & 7), sk1 = ((o1 >> 4) & 7) ^ (r1 & 7);
  const u16* kg0 = Kb + (size_t)(b * SEQ_LEN) * HID + h * HDIM + (size_t)r0 * HID + sk0 * 8;
  const u16* kg1 = Kb + (size_t)(b * SEQ_LEN) * HID + h * HDIM + (size_t)r1 * HID + sk1 * 8;
  const u16* vg0 = VT + ((size_t)(b * NHEAD + h) * HDIM + r0) * SEQ_LEN + sk0 * 8;
  const u16* vg1 = VT + ((size_t)(b * NHEAD + h) * HDIM + r1) * SEQ_LEN + sk1 * 8;

#define STAGE(BI)                                            \
  do {                                                       \
    gload16(kg0, lds + (BI) * 8192 + o0);                    \
    gload16(kg1, lds + (BI) * 8192 + o1);                    \
    gload16(vg0, lds + 16384 + (BI) * 8192 + o0);            \
    gload16(vg1, lds + 16384 + (BI) * 8192 + o1);            \
    kg0 += 64 * HID; kg1 += 64 * HID; vg0 += 64; vg1 += 64;  \
  } while (0)

#define COMPUTE(BI, KV0)                                                                   \
  do {                                                                                     \
    const char* Ks = lds + (BI) * 8192;                                                    \
    const char* Vs = lds + 16384 + (BI) * 8192;                                            \
    f32x4 sf[4];                                                                           \
    _Pragma("unroll") for (int kt = 0; kt < 4; kt++) sf[kt] = (f32x4){0.f, 0.f, 0.f, 0.f}; \
    _Pragma("unroll") for (int ks = 0; ks < 2; ks++) {                                     \
      _Pragma("unroll") for (int kt = 0; kt < 4; kt++) {                                   \
        bf16x8 kf = *(const bf16x8*)(Ks + off[ks][kt]);                                    \
        sf[kt] = __builtin_amdgcn_mfma_f32_16x16x32_bf16(kf, qf[ks], sf[kt], 0, 0, 0);     \
      }                                                                                    \
    }                                                                                      \
    if (useMask) {                                                                         \
      _Pragma("unroll") for (int kt = 0; kt < 4; kt++)                                     \
      _Pragma("unroll") for (int i = 0; i < 4; i++)                                        \
          sf[kt][i] += mask[(size_t)qrow * SEQ_LEN + (KV0) + kt * 16 + lg * 4 + i] * LOG2E;\
    }                                                                                      \
    float mx = fmaxf(fmaxf(fmaxf(sf[0][0], sf[0][1]), fmaxf(sf[0][2], sf[0][3])),          \
                     fmaxf(fmaxf(sf[1][0], sf[1][1]), fmaxf(sf[1][2], sf[1][3])));         \
    mx = fmaxf(mx, fmaxf(fmaxf(fmaxf(sf[2][0], sf[2][1]), fmaxf(sf[2][2], sf[2][3])),      \
                         fmaxf(fmaxf(sf[3][0], sf[3][1]), fmaxf(sf[3][2], sf[3][3]))));    \
    mx = fmaxf(mx, __shfl_xor(mx, 16));                                                    \
    mx = fmaxf(mx, __shfl_xor(mx, 32));                                                    \
    if (__any(mx > m_r + 8.0f)) {                                                          \
      float nm = fmaxf(m_r, mx);                                                           \
      float scf = exp2f(m_r - nm);                                                         \
      m_r = nm;                                                                            \
      _Pragma("unroll") for (int dt = 0; dt < 4; dt++)                                     \
      _Pragma("unroll") for (int i = 0; i < 4; i++) oacc[dt][i] *= scf;                    \
      lacc *= scf;                                                                         \
    }                                                                                      \
    _Pragma("unroll") for (int kt = 0; kt < 4; kt++)                                       \
    _Pragma("unroll") for (int i = 0; i < 4; i++) sf[kt][i] = exp2f(sf[kt][i] - m_r);      \
    _Pragma("unroll") for (int ks = 0; ks < 2; ks++) {                                     \
      bf16x8 pb;                                                                           \
      _Pragma("unroll") for (int j = 0; j < 4; j++) pb[j] = (__bf16)sf[2 * ks][j];         \
      _Pragma("unroll") for (int j = 0; j < 4; j++) pb[4 + j] = (__bf16)sf[2 * ks + 1][j]; \
      _Pragma("unroll") for (int dt = 0; dt < 4; dt++) {                                   \
        bf16x8 vf = *(const bf16x8*)(Vs + off[ks][dt]);                                    \
        oacc[dt] = __builtin_amdgcn_mfma_f32_16x16x32_bf16(vf, pb, oacc[dt], 0, 0, 0);     \
      }                                                                                    \
      lacc = __builtin_amdgcn_mfma_f32_16x16x32_bf16(ones, pb, lacc, 0, 0, 0);             \
    }                                                                                      \
  } while (0)

  STAGE(0);
  __syncthreads();

  const int NT = SEQ_LEN / 64;
  for (int t2 = 0; t2 < NT / 2; ++t2) {
    STAGE(1);
    COMPUTE(0, t2 * 128);
    __syncthreads();
    if (t2 != NT / 2 - 1) STAGE(0);
    COMPUTE(1, t2 * 128 + 64);
    __syncthreads();
  }
#undef STAGE
#undef COMPUTE

  // epilogue
  float inv = 1.0f / lacc[0];
  u16* orow = Ob + (size_t)(b * SEQ_LEN + qrow) * HID + h * HDIM;
#pragma unroll
  for (int dt = 0; dt < 4; dt++) {
    ushort4 pk = make_ushort4(f2bf(oacc[dt][0] * inv), f2bf(oacc[dt][1] * inv),
                              f2bf(oacc[dt][2] * inv), f2bf(oacc[dt][3] * inv));
    *(ushort4*)(orow + dt * 16 + lg * 4) = pk;
  }
}

// ---------------- launch ----------------

extern "C" void kernel_launch(void* const* d_in, const int* in_sizes, int n_in,
                              void* d_out, int out_size, void* d_ws, size_t ws_size,
                              hipStream_t stream) {
  const float* x    = (const float*)d_in[0];
  const float* mask = (const float*)d_in[1];
  const float* wq   = (const float*)d_in[2];
  const float* bq   = (const float*)d_in[3];
  const float* wk   = (const float*)d_in[4];
  const float* bk   = (const float*)d_in[5];
  const float* wv   = (const float*)d_in[6];
  const float* bv   = (const float*)d_in[7];
  const float* wo   = (const float*)d_in[8];
  const float* bo   = (const float*)d_in[9];

  char* ws = (char*)d_ws;
  u16* xb  = (u16*)(ws + 0);          // 16 MB (reused as Ob after QKV GEMM)
  u16* wqb = (u16*)(ws + 16777216);   // 2 MB each
  u16* wkb = (u16*)(ws + 18874368);
  u16* wvb = (u16*)(ws + 20971520);
  u16* wob = (u16*)(ws + 23068672);
  u16* Qb  = (u16*)(ws + 25165824);   // 16 MB
  u16* Kb  = (u16*)(ws + 41943040);   // 16 MB
  u16* VT  = (u16*)(ws + 58720256);   // 16 MB
  int* flag = (int*)(ws + 75497472);
  u16* Ob = xb;

  (void)hipMemsetAsync(flag, 0, 4, stream);
  cvt_x_kernel<<<2048, 256, 0, stream>>>(x, xb, MROWS * HID / 4);
  cvt_w_kernel<<<dim3(1024, 4), 256, 0, stream>>>(wq, wk, wv, wo, wqb);
  maskchk_kernel<<<2048, 256, 0, stream>>>(mask, SEQ_LEN * SEQ_LEN / 4, flag);
  gemm_qkv_kernel<<<dim3(64, 24), 256, 0, stream>>>(xb, wqb, wkb, wvb, bq, bk, bv, Qb, Kb, VT);
  attn_kernel<<<dim3(64, 32), 256, 0, stream>>>(Qb, Kb, VT, mask, flag, Ob);
  gemm_out_kernel<<<dim3(64, 8), 256, 0, stream>>>(Ob, wob, bo, (float*)d_out);
}